// Round 3
// baseline (206.820 us; speedup 1.0000x reference)
//
#include <hip/hip_runtime.h>
#include <hip/hip_bf16.h>

typedef __attribute__((ext_vector_type(8))) short bf16x8;
typedef __attribute__((ext_vector_type(4))) float f32x4;

#define SEQ 2048
#define DM  512
#define NH  8
#define DH  64
// (1/sqrt(2048)) * log2(e): folded into Q so scores come out ready for exp2
#define QSCALE 0.031879360f

__device__ __forceinline__ unsigned short f2bf(float f) {
  unsigned int u = __float_as_uint(f);
  unsigned int r = 0x7FFFu + ((u >> 16) & 1u);
  return (unsigned short)((u + r) >> 16);
}

// convert 2 float4 -> 8 bf16
__device__ __forceinline__ void cvt8f(const float4& v0, const float4& v1,
                                      unsigned short* __restrict__ o) {
  o[0] = f2bf(v0.x); o[1] = f2bf(v0.y); o[2] = f2bf(v0.z); o[3] = f2bf(v0.w);
  o[4] = f2bf(v1.x); o[5] = f2bf(v1.y); o[6] = f2bf(v1.z); o[7] = f2bf(v1.w);
}

// load 8 contiguous f32, convert to bf16
__device__ __forceinline__ void load8f(const float* __restrict__ s,
                                       unsigned short* __restrict__ o) {
  float4 v0 = *(const float4*)s;
  float4 v1 = *(const float4*)(s + 4);
  cvt8f(v0, v1, o);
}

// ---------- fused weight prep: Wq/Wk/Wv per-head transpose + Wo transpose (f32->bf16) ----------
// 256 blocks: [0,64) Wq, [64,128) Wk, [128,192) Wv, [192,256) Wo
__global__ __launch_bounds__(256) void weight_prep(const float* __restrict__ Wq,
                                                   const float* __restrict__ Wk,
                                                   const float* __restrict__ Wv,
                                                   const float* __restrict__ Wo,
                                                   unsigned short* __restrict__ Wqt,
                                                   unsigned short* __restrict__ Wkt,
                                                   unsigned short* __restrict__ Wvt,
                                                   unsigned short* __restrict__ Wot) {
  const int which = blockIdx.x >> 6, wi = blockIdx.x & 63;
  const float* src;
  unsigned short* dst;
  int R, C, r0, c0;
  if (which < 3) {
    const float* W = (which == 0) ? Wq : (which == 1) ? Wk : Wv;
    unsigned short* D = (which == 0) ? Wqt : (which == 1) ? Wkt : Wvt;
    int h = wi >> 3;
    src = W + (size_t)h * 512 * 64;
    dst = D + (size_t)h * 64 * 512;
    R = 512; C = 64; r0 = (wi & 7) * 64; c0 = 0;
  } else {
    src = Wo; dst = Wot;
    R = 512; C = 512; r0 = (wi >> 3) * 64; c0 = (wi & 7) * 64;
  }
  __shared__ __align__(16) unsigned short T[64][72];
  const int tid = threadIdx.x;
#pragma unroll
  for (int i = 0; i < 2; ++i) {
    int c = tid + 256 * i;
    int lr = c >> 3, lc = (c & 7) * 8;
    __align__(16) unsigned short tmp[8];
    load8f(src + (size_t)(r0 + lr) * C + c0 + lc, tmp);
    *(uint4*)&T[lr][lc] = *(const uint4*)tmp;
  }
  __syncthreads();
#pragma unroll
  for (int i = 0; i < 2; ++i) {
    int c = tid + 256 * i;
    int orow = c >> 3, och = (c & 7) * 8;
    __align__(16) unsigned short tmp[8];
#pragma unroll
    for (int j = 0; j < 8; ++j) tmp[j] = T[och + j][orow];
    *(uint4*)(dst + (size_t)(c0 + orow) * R + r0 + och) = *(uint4*)tmp;
  }
}

// ---------- fused QKV projection, 128x128 tiles, single-barrier double-buffered ----------
// z=0: Q (pre-scaled by QSCALE) -> Qp [B,H,S,64]; z=1: K -> Kp; z=2: V -> Vpt [B,H,64,S]
// Pipeline per K-step: write staged regs (tile k+1) -> issue loads (tile k+2) -> compute
// tile k -> ONE barrier. Raw float4s held in regs; f32->bf16 conversion deferred to the
// LDS-write a full iteration later so the waitcnt never stalls the issue point.
__global__ __launch_bounds__(256, 2) void proj128(const float* __restrict__ q,
                                                  const float* __restrict__ k,
                                                  const float* __restrict__ v,
                                                  const unsigned short* __restrict__ Wqt,
                                                  const unsigned short* __restrict__ Wkt,
                                                  const unsigned short* __restrict__ Wvt,
                                                  const float* __restrict__ bq,
                                                  const float* __restrict__ bk,
                                                  const float* __restrict__ bv,
                                                  unsigned short* __restrict__ Qp,
                                                  unsigned short* __restrict__ Kp,
                                                  unsigned short* __restrict__ Vpt) {
  const int which = blockIdx.z;
  const float* X = (which == 0) ? q : (which == 1) ? k : v;
  const unsigned short* Wt = (which == 0) ? Wqt : (which == 1) ? Wkt : Wvt;  // [512n][512k]
  const float* bias = (which == 0) ? bq : (which == 1) ? bk : bv;
  unsigned short* out = (which == 0) ? Qp : (which == 1) ? Kp : Vpt;
  const float ps = (which == 0) ? QSCALE : 1.0f;

  const int m0 = blockIdx.x * 128;
  const int n0 = blockIdx.y * 128;
  __shared__ __align__(16) unsigned short As[2][128][72], Bs[2][128][72];
  const int tid  = threadIdx.x;
  const int wave = tid >> 6, lane = tid & 63;
  const int l15  = lane & 15, quad = lane >> 4;
  const int rb = (wave >> 1) * 64, cb = (wave & 1) * 64;

  f32x4 acc[4][4];
#pragma unroll
  for (int i = 0; i < 4; ++i)
#pragma unroll
    for (int f = 0; f < 4; ++f) acc[i][f] = (f32x4){0.f, 0.f, 0.f, 0.f};

  // staging regs: per thread 4 A-chunks (2 float4 each) + 4 B-chunks (uint4 bf16)
  float4 af[4][2];
  uint4 bst[4];

#define P_LOAD(k0_) do {                                                        \
    _Pragma("unroll")                                                           \
    for (int i_ = 0; i_ < 4; ++i_) {                                            \
      int c_ = tid + 256 * i_;                                                  \
      int lr_ = c_ >> 3, lc_ = (c_ & 7) * 8;                                    \
      const float* xp_ = X + (size_t)(m0 + lr_) * DM + (k0_) + lc_;             \
      af[i_][0] = *(const float4*)xp_;                                          \
      af[i_][1] = *(const float4*)(xp_ + 4);                                    \
      bst[i_] = *(const uint4*)(Wt + (size_t)(n0 + lr_) * DM + (k0_) + lc_);    \
    } } while (0)

#define P_WRITE(bi_) do {                                                       \
    _Pragma("unroll")                                                           \
    for (int i_ = 0; i_ < 4; ++i_) {                                            \
      int c_ = tid + 256 * i_;                                                  \
      int lr_ = c_ >> 3, lc_ = (c_ & 7) * 8;                                    \
      __align__(16) unsigned short t_[8];                                       \
      cvt8f(af[i_][0], af[i_][1], t_);                                          \
      *(uint4*)&As[bi_][lr_][lc_] = *(const uint4*)t_;                          \
      *(uint4*)&Bs[bi_][lr_][lc_] = bst[i_];                                    \
    } } while (0)

  P_LOAD(0);
  P_WRITE(0);
  P_LOAD(64);
  __syncthreads();

#pragma unroll 1
  for (int k0i = 0; k0i < 8; ++k0i) {
    const int cur = k0i & 1;
    if (k0i < 7) P_WRITE(cur ^ 1);         // tile k0i+1 -> other buffer
    if (k0i < 6) P_LOAD((k0i + 2) * 64);   // tile k0i+2 -> regs
#pragma unroll
    for (int kc = 0; kc < 2; ++kc) {
      bf16x8 av[4], bv4[4];
#pragma unroll
      for (int i = 0; i < 4; ++i) av[i]  = *(const bf16x8*)&As[cur][rb + 16 * i + l15][kc * 32 + quad * 8];
#pragma unroll
      for (int f = 0; f < 4; ++f) bv4[f] = *(const bf16x8*)&Bs[cur][cb + 16 * f + l15][kc * 32 + quad * 8];
#pragma unroll
      for (int i = 0; i < 4; ++i)
#pragma unroll
        for (int f = 0; f < 4; ++f)
          acc[i][f] = __builtin_amdgcn_mfma_f32_16x16x32_bf16(av[i], bv4[f], acc[i][f], 0, 0, 0);
    }
    __syncthreads();
  }
#undef P_LOAD
#undef P_WRITE

  if (which < 2) {  // Q/K: [B,H,S,64]
#pragma unroll
    for (int i = 0; i < 4; ++i)
#pragma unroll
      for (int f = 0; f < 4; ++f)
#pragma unroll
        for (int r = 0; r < 4; ++r) {
          int m = m0 + rb + 16 * i + quad * 4 + r;
          int col = n0 + cb + 16 * f + l15;
          int head = col >> 6, o = col & 63;
          int b = m >> 11, s = m & (SEQ - 1);
          float val = (acc[i][f][r] + bias[col]) * ps;
          out[(((size_t)(b * NH + head) * SEQ + s) << 6) + o] = f2bf(val);
        }
  } else {  // V: emit V^T [B,H,64,S] via per-wave LDS bounce transpose
    __syncthreads();  // all waves done reading As/Bs
    unsigned short* T = &As[0][0][0] + wave * 4608;  // [64][72] per wave
#pragma unroll
    for (int i = 0; i < 4; ++i)
#pragma unroll
      for (int f = 0; f < 4; ++f)
#pragma unroll
        for (int r = 0; r < 4; ++r) {
          int lrow = 16 * i + quad * 4 + r;   // seq-local
          int lcol = 16 * f + l15;            // dh-local
          int col = n0 + cb + 16 * f + l15;
          T[lcol * 72 + lrow] = f2bf(acc[i][f][r] + bias[col]);
        }
    const int mbase = m0 + rb;
    const int b = mbase >> 11, sbase = mbase & (SEQ - 1);
    const int head = (n0 + cb) >> 6;
    unsigned short* dstb = out + ((size_t)(b * NH + head) * DH) * SEQ + sbase;
#pragma unroll
    for (int j = 0; j < 8; ++j) {
      int dh = (lane >> 3) + j * 8;
      int sc = (lane & 7) * 8;
      *(uint4*)(dstb + (size_t)dh * SEQ + sc) = *(const uint4*)&T[dh * 72 + sc];
    }
  }
}

// ---------- flash attention (no-max exp2 softmax) -> concat bf16 [B,SEQ,DM] ----------
// Qp pre-scaled by QSCALE. Causal-pairing block (bh, ip): q-tiles qa=ip, qb=31-ip.
// 8 waves: 0-3 own qb row-quarters, 4-7 own qa. Single barrier/iter, dbuf K/V,
// loads issued 2 tiles ahead. grid x=bh -> same-bh blocks share an XCD (L2-resident K/V).
// Ps row stride 76 shorts (38 dwords == 6 mod 32): the 16 ds_write_b16 P-writes per
// wave-iter hit all 32 banks (was 16 banks / 4-way at stride 72 -> 4.87M conflict cycles).
__global__ __launch_bounds__(512, 4) void attn_kernel(const unsigned short* __restrict__ Qp,
                                                      const unsigned short* __restrict__ Kp,
                                                      const unsigned short* __restrict__ Vpt,
                                                      unsigned short* __restrict__ concat) {
  const int bh = blockIdx.x;            // 32
  const int ip = blockIdx.y;            // pair index 0..15
  const int b = bh >> 3, h = bh & 7;
  const int qa = ip, qb = 31 - ip;      // qa < qb always
  __shared__ __align__(16) unsigned short Ks[2][64][72], Vts[2][64][72], Ps[128][76];
  const int tid  = threadIdx.x;
  const int wave = tid >> 6, lane = tid & 63;
  const int l15  = lane & 15, quad = lane >> 4;
  const int w4   = wave & 3;
  const bool isB = wave < 4;            // waves 0-3 -> qb, waves 4-7 -> qa
  const int qt   = isB ? qb : qa;
  const unsigned short* Qb = Qp  + (size_t)bh * SEQ * DH;
  const unsigned short* Kb = Kp  + (size_t)bh * SEQ * DH;
  const unsigned short* Vb = Vpt + (size_t)bh * DH * SEQ;

  // own q-tile fragments straight to registers (16 rows per wave)
  bf16x8 aq[2];
#pragma unroll
  for (int kc = 0; kc < 2; ++kc)
    aq[kc] = *(const bf16x8*)(Qb + (size_t)(qt * 64 + 16 * w4 + l15) * DH + kc * 32 + quad * 8);

  float l_lane[4];
  f32x4 Of[4];
#pragma unroll
  for (int r = 0; r < 4; ++r) l_lane[r] = 0.f;
#pragma unroll
  for (int f = 0; f < 4; ++f) Of[f] = (f32x4){0.f, 0.f, 0.f, 0.f};

  // staging: K tile 64x64 bf16 = 512 uint4 chunks; 512 threads own 1 chunk each (K and V)
  const int sr = tid >> 3, sc = (tid & 7) * 8;
  uint4 kst, vst;

#define STAGE_LOAD(lt_) do {                                                   \
    kst = *(const uint4*)(Kb + (size_t)((lt_) * 64 + sr) * DH + sc);           \
    vst = *(const uint4*)(Vb + (size_t)sr * SEQ + (lt_) * 64 + sc);            \
  } while (0)

#define STAGE_WRITE(bi_) do {                                                  \
    *(uint4*)&Ks[bi_][sr][sc]  = kst;                                          \
    *(uint4*)&Vts[bi_][sr][sc] = vst;                                          \
  } while (0)

  // prologue: tile 0 -> buf 0; tile 1 -> regs (qb >= 16 so tiles 0,1 always exist)
  STAGE_LOAD(0);
  STAGE_WRITE(0);
  STAGE_LOAD(1);
  __syncthreads();

#pragma unroll 1
  for (int lt = 0; lt <= qb; ++lt) {
    const int cur = lt & 1;
    // write staged regs (tile lt+1) into other buffer; prev iter's end barrier
    // guarantees its readers are done
    if (lt < qb) STAGE_WRITE(cur ^ 1);
    // issue global loads for tile lt+2 -> latency hides under this iter's compute
    if (lt + 2 <= qb) STAGE_LOAD(lt + 2);

    const bool act = isB || (lt <= qa);
    if (act) {
      const int l0 = lt * 64;
      // S' = (Q*QSCALE) K^T  (already includes log2e)
      f32x4 S[4];
#pragma unroll
      for (int f = 0; f < 4; ++f) S[f] = (f32x4){0.f, 0.f, 0.f, 0.f};
#pragma unroll
      for (int kc = 0; kc < 2; ++kc) {
#pragma unroll
        for (int f = 0; f < 4; ++f) {
          bf16x8 bk = *(const bf16x8*)&Ks[cur][16 * f + l15][kc * 32 + quad * 8];
          S[f] = __builtin_amdgcn_mfma_f32_16x16x32_bf16(aq[kc], bk, S[f], 0, 0, 0);
        }
      }
      if (lt == qt) {
        const int mrow = qt * 64 + 16 * w4 + quad * 4;
#pragma unroll
        for (int f = 0; f < 4; ++f)
#pragma unroll
          for (int r = 0; r < 4; ++r)
            if (l0 + 16 * f + l15 > mrow + r) S[f][r] = -1e30f;
      }
      // p = exp2(S'), accumulate per-lane row partial sums (reduced once at end)
#pragma unroll
      for (int f = 0; f < 4; ++f)
#pragma unroll
        for (int r = 0; r < 4; ++r) {
          float p = __builtin_amdgcn_exp2f(S[f][r]);
          l_lane[r] += p;
          Ps[wave * 16 + quad * 4 + r][16 * f + l15] = f2bf(p);  // wave-private rows
        }
      // O += P @ V
#pragma unroll
      for (int kc = 0; kc < 2; ++kc) {
        bf16x8 ap = *(const bf16x8*)&Ps[wave * 16 + l15][kc * 32 + quad * 8];
#pragma unroll
        for (int f = 0; f < 4; ++f) {
          bf16x8 bvv = *(const bf16x8*)&Vts[cur][16 * f + l15][kc * 32 + quad * 8];
          Of[f] = __builtin_amdgcn_mfma_f32_16x16x32_bf16(ap, bvv, Of[f], 0, 0, 0);
        }
      }
    }
    __syncthreads();
  }
#undef STAGE_LOAD
#undef STAGE_WRITE

  // row-sum reduction across the 16 lanes sharing each row
#pragma unroll
  for (int d = 1; d < 16; d <<= 1)
#pragma unroll
    for (int r = 0; r < 4; ++r) l_lane[r] += __shfl_xor(l_lane[r], d);

#pragma unroll
  for (int f = 0; f < 4; ++f)
#pragma unroll
    for (int r = 0; r < 4; ++r) {
      const int row = qt * 64 + 16 * w4 + quad * 4 + r;
      const int col = h * DH + 16 * f + l15;
      concat[(size_t)(b * SEQ + row) * DM + col] = f2bf(Of[f][r] / l_lane[r]);
    }
}

// ---------- output projection: out_f32 = concat_bf16 @ Wot^T + b_o ----------
// Single-barrier double-buffered B staging; 16 fully-unrolled (n0,k0) steps so the
// accumulator indices stay compile-time (no scratch). grid (128,4): 512 blocks, 2/CU.
__global__ __launch_bounds__(256, 2) void gemm_out(const unsigned short* __restrict__ A,
                                                   const unsigned short* __restrict__ Bt,
                                                   const float* __restrict__ bias,
                                                   float* __restrict__ out) {
  const int m0 = blockIdx.x * 64;
  const int nbase = blockIdx.y * 128;
  __shared__ __align__(16) unsigned short Bs[2][64][72];
  const int tid  = threadIdx.x;
  const int wave = tid >> 6, lane = tid & 63;
  const int l15  = lane & 15, quad = lane >> 4;

  bf16x8 afr[16];  // per-wave A rows held in registers across all steps
  const unsigned short* arow = A + (size_t)(m0 + 16 * wave + l15) * DM;
#pragma unroll
  for (int k0i = 0; k0i < 8; ++k0i)
#pragma unroll
    for (int kc = 0; kc < 2; ++kc)
      afr[k0i * 2 + kc] = *(const bf16x8*)(arow + k0i * 64 + kc * 32 + quad * 8);

  uint4 bst0, bst1;
  const int br = tid >> 3, bc = (tid & 7) * 8;

#define G_LOAD(s_) do {                                                          \
    const int n0_ = nbase + ((s_) >> 3) * 64, k0_ = ((s_) & 7) * 64;             \
    bst0 = *(const uint4*)(Bt + (size_t)(n0_ + br) * DM + k0_ + bc);             \
    bst1 = *(const uint4*)(Bt + (size_t)(n0_ + br + 32) * DM + k0_ + bc);        \
  } while (0)

#define G_WRITE(bi_) do {                                                        \
    *(uint4*)&Bs[bi_][br][bc]      = bst0;                                       \
    *(uint4*)&Bs[bi_][br + 32][bc] = bst1;                                       \
  } while (0)

  f32x4 acc[2][4];
#pragma unroll
  for (int nh = 0; nh < 2; ++nh)
#pragma unroll
    for (int f = 0; f < 4; ++f) acc[nh][f] = (f32x4){0.f, 0.f, 0.f, 0.f};

  G_LOAD(0);
  G_WRITE(0);
  G_LOAD(1);
  __syncthreads();

#pragma unroll
  for (int s = 0; s < 16; ++s) {   // full unroll: s, nh, cur all compile-time
    const int cur = s & 1;
    if (s < 15) G_WRITE(cur ^ 1);
    if (s < 14) G_LOAD(s + 2);
    const int nh = s >> 3, k0i = s & 7;
#pragma unroll
    for (int kc = 0; kc < 2; ++kc)
#pragma unroll
      for (int f = 0; f < 4; ++f) {
        bf16x8 bfv = *(const bf16x8*)&Bs[cur][16 * f + l15][kc * 32 + quad * 8];
        acc[nh][f] = __builtin_amdgcn_mfma_f32_16x16x32_bf16(afr[k0i * 2 + kc], bfv, acc[nh][f], 0, 0, 0);
      }
    __syncthreads();
  }
#undef G_LOAD
#undef G_WRITE

#pragma unroll
  for (int nh = 0; nh < 2; ++nh)
#pragma unroll
    for (int f = 0; f < 4; ++f)
#pragma unroll
      for (int r = 0; r < 4; ++r) {
        int row = 16 * wave + quad * 4 + r;
        int col = nbase + nh * 64 + 16 * f + l15;
        out[(size_t)(m0 + row) * DM + col] = acc[nh][f][r] + bias[col];
      }
}

extern "C" void kernel_launch(void* const* d_in, const int* in_sizes, int n_in,
                              void* d_out, int out_size, void* d_ws, size_t ws_size,
                              hipStream_t stream) {
  const float* query = (const float*)d_in[0];
  const float* key   = (const float*)d_in[1];
  const float* value = (const float*)d_in[2];
  const float* W_q   = (const float*)d_in[3];
  const float* b_q   = (const float*)d_in[4];
  const float* W_k   = (const float*)d_in[5];
  const float* b_k   = (const float*)d_in[6];
  const float* W_v   = (const float*)d_in[7];
  const float* b_v   = (const float*)d_in[8];
  const float* W_o   = (const float*)d_in[9];
  const float* b_o   = (const float*)d_in[10];
  float* out = (float*)d_out;

  char* ws = (char*)d_ws;
  unsigned short* Wqt    = (unsigned short*)(ws + 0);         // [H][64][512] bf16
  unsigned short* Wkt    = (unsigned short*)(ws + 524288);
  unsigned short* Wvt    = (unsigned short*)(ws + 1048576);
  unsigned short* Wot    = (unsigned short*)(ws + 1572864);   // [512][512] bf16
  unsigned short* Qp     = (unsigned short*)(ws + 2097152);   // [B,H,S,64] bf16 8 MB
  unsigned short* Kp     = (unsigned short*)(ws + 10485760);
  unsigned short* Vpt    = (unsigned short*)(ws + 18874368);  // [B,H,64,S] bf16 8 MB
  unsigned short* concat = (unsigned short*)(ws + 27262976);  // [B,S,512] bf16 8 MB

  weight_prep<<<dim3(256), 256, 0, stream>>>(W_q, W_k, W_v, W_o, Wqt, Wkt, Wvt, Wot);

  proj128<<<dim3(64, 4, 3), 256, 0, stream>>>(query, key, value, Wqt, Wkt, Wvt,
                                              b_q, b_k, b_v, Qp, Kp, Vpt);

  attn_kernel<<<dim3(32, 16), 512, 0, stream>>>(Qp, Kp, Vpt, concat);

  gemm_out<<<dim3(128, 4), 256, 0, stream>>>(concat, Wot, b_o, out);
}

// Round 4
// 184.010 us; speedup vs baseline: 1.1240x; 1.1240x over previous
//
#include <hip/hip_runtime.h>
#include <hip/hip_bf16.h>

typedef __attribute__((ext_vector_type(8))) short bf16x8;
typedef __attribute__((ext_vector_type(4))) float f32x4;

#define SEQ 2048
#define DM  512
#define NH  8
#define DH  64
// (1/sqrt(2048)) * log2(e): folded into Q so scores come out ready for exp2
#define QSCALE 0.031879360f

__device__ __forceinline__ unsigned short f2bf(float f) {
  unsigned int u = __float_as_uint(f);
  unsigned int r = 0x7FFFu + ((u >> 16) & 1u);
  return (unsigned short)((u + r) >> 16);
}

// convert 2 float4 -> 8 bf16
__device__ __forceinline__ void cvt8f(const float4& v0, const float4& v1,
                                      unsigned short* __restrict__ o) {
  o[0] = f2bf(v0.x); o[1] = f2bf(v0.y); o[2] = f2bf(v0.z); o[3] = f2bf(v0.w);
  o[4] = f2bf(v1.x); o[5] = f2bf(v1.y); o[6] = f2bf(v1.z); o[7] = f2bf(v1.w);
}

// load 8 contiguous f32, convert to bf16
__device__ __forceinline__ void load8f(const float* __restrict__ s,
                                       unsigned short* __restrict__ o) {
  float4 v0 = *(const float4*)s;
  float4 v1 = *(const float4*)(s + 4);
  cvt8f(v0, v1, o);
}

// ---------- fused weight prep + X conversion ----------
// blocks [0,256): Wq/Wk/Wv per-head transpose + Wo transpose (f32->bf16)
// blocks [256,640): stream-convert query/key/value f32 -> bf16 into Xb[3][B*SEQ*DM]
//   (hoists the f32->bf16 conversion OUT of proj128, where it ran 4x per element and
//    forced fat f32 staging registers -> spills in round 3)
__global__ __launch_bounds__(256) void weight_prep(const float* __restrict__ Wq,
                                                   const float* __restrict__ Wk,
                                                   const float* __restrict__ Wv,
                                                   const float* __restrict__ Wo,
                                                   const float* __restrict__ q,
                                                   const float* __restrict__ k,
                                                   const float* __restrict__ v,
                                                   unsigned short* __restrict__ Wqt,
                                                   unsigned short* __restrict__ Wkt,
                                                   unsigned short* __restrict__ Wvt,
                                                   unsigned short* __restrict__ Wot,
                                                   unsigned short* __restrict__ Xb) {
  const int tid = threadIdx.x;
  if (blockIdx.x >= 256) {
    const int wi = blockIdx.x - 256;                 // 0..383
    const float* src = (wi < 128) ? q : (wi < 256) ? k : v;
    const size_t off = (size_t)(wi & 127) * 32768;   // 128 blocks x 32768 = 4194304 elems/slice
    const float* s = src + off;
    unsigned short* d = Xb + (size_t)(wi >> 7) * (4u * SEQ * DM) + off;
#pragma unroll
    for (int i = 0; i < 16; ++i) {
      const size_t idx = (size_t)(tid + 256 * i) * 8;
      __align__(16) unsigned short t[8];
      load8f(s + idx, t);
      *(uint4*)(d + idx) = *(const uint4*)t;
    }
    return;
  }
  const int which = blockIdx.x >> 6, wi = blockIdx.x & 63;
  const float* src;
  unsigned short* dst;
  int R, C, r0, c0;
  if (which < 3) {
    const float* W = (which == 0) ? Wq : (which == 1) ? Wk : Wv;
    unsigned short* D = (which == 0) ? Wqt : (which == 1) ? Wkt : Wvt;
    int h = wi >> 3;
    src = W + (size_t)h * 512 * 64;
    dst = D + (size_t)h * 64 * 512;
    R = 512; C = 64; r0 = (wi & 7) * 64; c0 = 0;
  } else {
    src = Wo; dst = Wot;
    R = 512; C = 512; r0 = (wi >> 3) * 64; c0 = (wi & 7) * 64;
  }
  __shared__ __align__(16) unsigned short T[64][72];
#pragma unroll
  for (int i = 0; i < 2; ++i) {
    int c = tid + 256 * i;
    int lr = c >> 3, lc = (c & 7) * 8;
    __align__(16) unsigned short tmp[8];
    load8f(src + (size_t)(r0 + lr) * C + c0 + lc, tmp);
    *(uint4*)&T[lr][lc] = *(const uint4*)tmp;
  }
  __syncthreads();
#pragma unroll
  for (int i = 0; i < 2; ++i) {
    int c = tid + 256 * i;
    int orow = c >> 3, och = (c & 7) * 8;
    __align__(16) unsigned short tmp[8];
#pragma unroll
    for (int j = 0; j < 8; ++j) tmp[j] = T[och + j][orow];
    *(uint4*)(dst + (size_t)(c0 + orow) * R + r0 + och) = *(uint4*)tmp;
  }
}

// ---------- fused QKV projection, 128x128 tiles, pure-bf16 GEMM ----------
// z=0: Q (pre-scaled by QSCALE) -> Qp [B,H,S,64]; z=1: K -> Kp; z=2: V -> Vpt [B,H,64,S]
// Round-2 structure (2 barriers/K-step, single LDS buffer, 4 blocks/CU) but A is
// pre-converted bf16 -> staging is 8 plain uint4 copies/thread/step, no VALU conversion,
// no spill (round-3 dbuf+f32-staging regressed: 2 blocks/CU + 27MB scratch writes).
__global__ __launch_bounds__(256, 4) void proj128(const unsigned short* __restrict__ Xb,
                                                  const unsigned short* __restrict__ Wqt,
                                                  const unsigned short* __restrict__ Wkt,
                                                  const unsigned short* __restrict__ Wvt,
                                                  const float* __restrict__ bq,
                                                  const float* __restrict__ bk,
                                                  const float* __restrict__ bv,
                                                  unsigned short* __restrict__ Qp,
                                                  unsigned short* __restrict__ Kp,
                                                  unsigned short* __restrict__ Vpt) {
  const int which = blockIdx.z;
  const unsigned short* X = Xb + (size_t)which * (4u * SEQ * DM);
  const unsigned short* Wt = (which == 0) ? Wqt : (which == 1) ? Wkt : Wvt;  // [512n][512k]
  const float* bias = (which == 0) ? bq : (which == 1) ? bk : bv;
  unsigned short* out = (which == 0) ? Qp : (which == 1) ? Kp : Vpt;
  const float ps = (which == 0) ? QSCALE : 1.0f;

  const int m0 = blockIdx.x * 128;
  const int n0 = blockIdx.y * 128;
  __shared__ __align__(16) unsigned short smem[2][128][72];
  unsigned short (*As)[72] = smem[0];
  unsigned short (*Bs)[72] = smem[1];
  const int tid  = threadIdx.x;
  const int wave = tid >> 6, lane = tid & 63;
  const int l15  = lane & 15, quad = lane >> 4;
  const int rb = (wave >> 1) * 64, cb = (wave & 1) * 64;

  f32x4 acc[4][4];
#pragma unroll
  for (int i = 0; i < 4; ++i)
#pragma unroll
    for (int f = 0; f < 4; ++f) acc[i][f] = (f32x4){0.f, 0.f, 0.f, 0.f};

  for (int k0 = 0; k0 < DM; k0 += 64) {
    __syncthreads();
#pragma unroll
    for (int i = 0; i < 4; ++i) {
      int c = tid + 256 * i;             // 1024 slots x 8 elems = 128x64
      int lr = c >> 3, lc = (c & 7) * 8;
      *(uint4*)&As[lr][lc] = *(const uint4*)(X  + (size_t)(m0 + lr) * DM + k0 + lc);
      *(uint4*)&Bs[lr][lc] = *(const uint4*)(Wt + (size_t)(n0 + lr) * DM + k0 + lc);
    }
    __syncthreads();
#pragma unroll
    for (int kc = 0; kc < 2; ++kc) {
      bf16x8 av[4], bv4[4];
#pragma unroll
      for (int i = 0; i < 4; ++i) av[i]  = *(const bf16x8*)&As[rb + 16 * i + l15][kc * 32 + quad * 8];
#pragma unroll
      for (int f = 0; f < 4; ++f) bv4[f] = *(const bf16x8*)&Bs[cb + 16 * f + l15][kc * 32 + quad * 8];
#pragma unroll
      for (int i = 0; i < 4; ++i)
#pragma unroll
        for (int f = 0; f < 4; ++f)
          acc[i][f] = __builtin_amdgcn_mfma_f32_16x16x32_bf16(av[i], bv4[f], acc[i][f], 0, 0, 0);
    }
  }

  if (which < 2) {  // Q/K: [B,H,S,64]
#pragma unroll
    for (int i = 0; i < 4; ++i)
#pragma unroll
      for (int f = 0; f < 4; ++f)
#pragma unroll
        for (int r = 0; r < 4; ++r) {
          int m = m0 + rb + 16 * i + quad * 4 + r;
          int col = n0 + cb + 16 * f + l15;
          int head = col >> 6, o = col & 63;
          int b = m >> 11, s = m & (SEQ - 1);
          float val = (acc[i][f][r] + bias[col]) * ps;
          out[(((size_t)(b * NH + head) * SEQ + s) << 6) + o] = f2bf(val);
        }
  } else {  // V: emit V^T [B,H,64,S] via per-wave LDS bounce transpose
    __syncthreads();  // all waves done reading As/Bs
    unsigned short* T = &smem[0][0][0] + wave * 4608;  // [64][72] per wave
#pragma unroll
    for (int i = 0; i < 4; ++i)
#pragma unroll
      for (int f = 0; f < 4; ++f)
#pragma unroll
        for (int r = 0; r < 4; ++r) {
          int lrow = 16 * i + quad * 4 + r;   // seq-local
          int lcol = 16 * f + l15;            // dh-local
          int col = n0 + cb + 16 * f + l15;
          T[lcol * 72 + lrow] = f2bf(acc[i][f][r] + bias[col]);
        }
    const int mbase = m0 + rb;
    const int b = mbase >> 11, sbase = mbase & (SEQ - 1);
    const int head = (n0 + cb) >> 6;
    unsigned short* dstb = out + ((size_t)(b * NH + head) * DH) * SEQ + sbase;
#pragma unroll
    for (int j = 0; j < 8; ++j) {
      int dh = (lane >> 3) + j * 8;
      int sc = (lane & 7) * 8;
      *(uint4*)(dstb + (size_t)dh * SEQ + sc) = *(const uint4*)&T[dh * 72 + sc];
    }
  }
}

// ---------- flash attention (no-max exp2 softmax) -> concat bf16 [B,SEQ,DM] ----------
// Qp pre-scaled by QSCALE. Causal-pairing block (bh, ip): q-tiles qa=ip, qb=31-ip.
// 8 waves: 0-3 own qb row-quarters, 4-7 own qa. Single barrier/iter, dbuf K/V,
// loads issued 2 tiles ahead. grid x=bh -> same-bh blocks share an XCD (L2-resident K/V).
// Ps row stride 76 shorts (38 dwords == 6 mod 32): the 16 ds_write_b16 P-writes per
// wave-iter hit all 32 banks (was 16 banks / 4-way at stride 72 -> 4.87M conflict cycles).
__global__ __launch_bounds__(512, 4) void attn_kernel(const unsigned short* __restrict__ Qp,
                                                      const unsigned short* __restrict__ Kp,
                                                      const unsigned short* __restrict__ Vpt,
                                                      unsigned short* __restrict__ concat) {
  const int bh = blockIdx.x;            // 32
  const int ip = blockIdx.y;            // pair index 0..15
  const int b = bh >> 3, h = bh & 7;
  const int qa = ip, qb = 31 - ip;      // qa < qb always
  __shared__ __align__(16) unsigned short Ks[2][64][72], Vts[2][64][72], Ps[128][76];
  const int tid  = threadIdx.x;
  const int wave = tid >> 6, lane = tid & 63;
  const int l15  = lane & 15, quad = lane >> 4;
  const int w4   = wave & 3;
  const bool isB = wave < 4;            // waves 0-3 -> qb, waves 4-7 -> qa
  const int qt   = isB ? qb : qa;
  const unsigned short* Qb = Qp  + (size_t)bh * SEQ * DH;
  const unsigned short* Kb = Kp  + (size_t)bh * SEQ * DH;
  const unsigned short* Vb = Vpt + (size_t)bh * DH * SEQ;

  // own q-tile fragments straight to registers (16 rows per wave)
  bf16x8 aq[2];
#pragma unroll
  for (int kc = 0; kc < 2; ++kc)
    aq[kc] = *(const bf16x8*)(Qb + (size_t)(qt * 64 + 16 * w4 + l15) * DH + kc * 32 + quad * 8);

  float l_lane[4];
  f32x4 Of[4];
#pragma unroll
  for (int r = 0; r < 4; ++r) l_lane[r] = 0.f;
#pragma unroll
  for (int f = 0; f < 4; ++f) Of[f] = (f32x4){0.f, 0.f, 0.f, 0.f};

  // staging: K tile 64x64 bf16 = 512 uint4 chunks; 512 threads own 1 chunk each (K and V)
  const int sr = tid >> 3, sc = (tid & 7) * 8;
  uint4 kst, vst;

#define STAGE_LOAD(lt_) do {                                                   \
    kst = *(const uint4*)(Kb + (size_t)((lt_) * 64 + sr) * DH + sc);           \
    vst = *(const uint4*)(Vb + (size_t)sr * SEQ + (lt_) * 64 + sc);            \
  } while (0)

#define STAGE_WRITE(bi_) do {                                                  \
    *(uint4*)&Ks[bi_][sr][sc]  = kst;                                          \
    *(uint4*)&Vts[bi_][sr][sc] = vst;                                          \
  } while (0)

  // prologue: tile 0 -> buf 0; tile 1 -> regs (qb >= 16 so tiles 0,1 always exist)
  STAGE_LOAD(0);
  STAGE_WRITE(0);
  STAGE_LOAD(1);
  __syncthreads();

#pragma unroll 1
  for (int lt = 0; lt <= qb; ++lt) {
    const int cur = lt & 1;
    // write staged regs (tile lt+1) into other buffer; prev iter's end barrier
    // guarantees its readers are done
    if (lt < qb) STAGE_WRITE(cur ^ 1);
    // issue global loads for tile lt+2 -> latency hides under this iter's compute
    if (lt + 2 <= qb) STAGE_LOAD(lt + 2);

    const bool act = isB || (lt <= qa);
    if (act) {
      const int l0 = lt * 64;
      // S' = (Q*QSCALE) K^T  (already includes log2e)
      f32x4 S[4];
#pragma unroll
      for (int f = 0; f < 4; ++f) S[f] = (f32x4){0.f, 0.f, 0.f, 0.f};
#pragma unroll
      for (int kc = 0; kc < 2; ++kc) {
#pragma unroll
        for (int f = 0; f < 4; ++f) {
          bf16x8 bk = *(const bf16x8*)&Ks[cur][16 * f + l15][kc * 32 + quad * 8];
          S[f] = __builtin_amdgcn_mfma_f32_16x16x32_bf16(aq[kc], bk, S[f], 0, 0, 0);
        }
      }
      if (lt == qt) {
        const int mrow = qt * 64 + 16 * w4 + quad * 4;
#pragma unroll
        for (int f = 0; f < 4; ++f)
#pragma unroll
          for (int r = 0; r < 4; ++r)
            if (l0 + 16 * f + l15 > mrow + r) S[f][r] = -1e30f;
      }
      // p = exp2(S'), accumulate per-lane row partial sums (reduced once at end)
#pragma unroll
      for (int f = 0; f < 4; ++f)
#pragma unroll
        for (int r = 0; r < 4; ++r) {
          float p = __builtin_amdgcn_exp2f(S[f][r]);
          l_lane[r] += p;
          Ps[wave * 16 + quad * 4 + r][16 * f + l15] = f2bf(p);  // wave-private rows
        }
      // O += P @ V
#pragma unroll
      for (int kc = 0; kc < 2; ++kc) {
        bf16x8 ap = *(const bf16x8*)&Ps[wave * 16 + l15][kc * 32 + quad * 8];
#pragma unroll
        for (int f = 0; f < 4; ++f) {
          bf16x8 bvv = *(const bf16x8*)&Vts[cur][16 * f + l15][kc * 32 + quad * 8];
          Of[f] = __builtin_amdgcn_mfma_f32_16x16x32_bf16(ap, bvv, Of[f], 0, 0, 0);
        }
      }
    }
    __syncthreads();
  }
#undef STAGE_LOAD
#undef STAGE_WRITE

  // row-sum reduction across the 16 lanes sharing each row
#pragma unroll
  for (int d = 1; d < 16; d <<= 1)
#pragma unroll
    for (int r = 0; r < 4; ++r) l_lane[r] += __shfl_xor(l_lane[r], d);

#pragma unroll
  for (int f = 0; f < 4; ++f)
#pragma unroll
    for (int r = 0; r < 4; ++r) {
      const int row = qt * 64 + 16 * w4 + quad * 4 + r;
      const int col = h * DH + 16 * f + l15;
      concat[(size_t)(b * SEQ + row) * DM + col] = f2bf(Of[f][r] / l_lane[r]);
    }
}

// ---------- output projection: out_f32 = concat_bf16 @ Wot^T + b_o ----------
// Single-barrier double-buffered B staging; 16 fully-unrolled (n0,k0) steps so the
// accumulator indices stay compile-time (no scratch). grid (128,4): 512 blocks, 2/CU.
__global__ __launch_bounds__(256, 2) void gemm_out(const unsigned short* __restrict__ A,
                                                   const unsigned short* __restrict__ Bt,
                                                   const float* __restrict__ bias,
                                                   float* __restrict__ out) {
  const int m0 = blockIdx.x * 64;
  const int nbase = blockIdx.y * 128;
  __shared__ __align__(16) unsigned short Bs[2][64][72];
  const int tid  = threadIdx.x;
  const int wave = tid >> 6, lane = tid & 63;
  const int l15  = lane & 15, quad = lane >> 4;

  bf16x8 afr[16];  // per-wave A rows held in registers across all steps
  const unsigned short* arow = A + (size_t)(m0 + 16 * wave + l15) * DM;
#pragma unroll
  for (int k0i = 0; k0i < 8; ++k0i)
#pragma unroll
    for (int kc = 0; kc < 2; ++kc)
      afr[k0i * 2 + kc] = *(const bf16x8*)(arow + k0i * 64 + kc * 32 + quad * 8);

  uint4 bst0, bst1;
  const int br = tid >> 3, bc = (tid & 7) * 8;

#define G_LOAD(s_) do {                                                          \
    const int n0_ = nbase + ((s_) >> 3) * 64, k0_ = ((s_) & 7) * 64;             \
    bst0 = *(const uint4*)(Bt + (size_t)(n0_ + br) * DM + k0_ + bc);             \
    bst1 = *(const uint4*)(Bt + (size_t)(n0_ + br + 32) * DM + k0_ + bc);        \
  } while (0)

#define G_WRITE(bi_) do {                                                        \
    *(uint4*)&Bs[bi_][br][bc]      = bst0;                                       \
    *(uint4*)&Bs[bi_][br + 32][bc] = bst1;                                       \
  } while (0)

  f32x4 acc[2][4];
#pragma unroll
  for (int nh = 0; nh < 2; ++nh)
#pragma unroll
    for (int f = 0; f < 4; ++f) acc[nh][f] = (f32x4){0.f, 0.f, 0.f, 0.f};

  G_LOAD(0);
  G_WRITE(0);
  G_LOAD(1);
  __syncthreads();

#pragma unroll
  for (int s = 0; s < 16; ++s) {   // full unroll: s, nh, cur all compile-time
    const int cur = s & 1;
    if (s < 15) G_WRITE(cur ^ 1);
    if (s < 14) G_LOAD(s + 2);
    const int nh = s >> 3, k0i = s & 7;
#pragma unroll
    for (int kc = 0; kc < 2; ++kc)
#pragma unroll
      for (int f = 0; f < 4; ++f) {
        bf16x8 bfv = *(const bf16x8*)&Bs[cur][16 * f + l15][kc * 32 + quad * 8];
        acc[nh][f] = __builtin_amdgcn_mfma_f32_16x16x32_bf16(afr[k0i * 2 + kc], bfv, acc[nh][f], 0, 0, 0);
      }
    __syncthreads();
  }
#undef G_LOAD
#undef G_WRITE

#pragma unroll
  for (int nh = 0; nh < 2; ++nh)
#pragma unroll
    for (int f = 0; f < 4; ++f)
#pragma unroll
      for (int r = 0; r < 4; ++r) {
        int row = 16 * wave + quad * 4 + r;
        int col = nbase + nh * 64 + 16 * f + l15;
        out[(size_t)(m0 + row) * DM + col] = acc[nh][f][r] + bias[col];
      }
}

extern "C" void kernel_launch(void* const* d_in, const int* in_sizes, int n_in,
                              void* d_out, int out_size, void* d_ws, size_t ws_size,
                              hipStream_t stream) {
  const float* query = (const float*)d_in[0];
  const float* key   = (const float*)d_in[1];
  const float* value = (const float*)d_in[2];
  const float* W_q   = (const float*)d_in[3];
  const float* b_q   = (const float*)d_in[4];
  const float* W_k   = (const float*)d_in[5];
  const float* b_k   = (const float*)d_in[6];
  const float* W_v   = (const float*)d_in[7];
  const float* b_v   = (const float*)d_in[8];
  const float* W_o   = (const float*)d_in[9];
  const float* b_o   = (const float*)d_in[10];
  float* out = (float*)d_out;

  char* ws = (char*)d_ws;
  unsigned short* Wqt    = (unsigned short*)(ws + 0);         // [H][64][512] bf16
  unsigned short* Wkt    = (unsigned short*)(ws + 524288);
  unsigned short* Wvt    = (unsigned short*)(ws + 1048576);
  unsigned short* Wot    = (unsigned short*)(ws + 1572864);   // [512][512] bf16
  unsigned short* Qp     = (unsigned short*)(ws + 2097152);   // [B,H,S,64] bf16 8 MB
  unsigned short* Kp     = (unsigned short*)(ws + 10485760);
  unsigned short* Vpt    = (unsigned short*)(ws + 18874368);  // [B,H,64,S] bf16 8 MB
  unsigned short* concat = (unsigned short*)(ws + 27262976);  // [B,S,512] bf16 8 MB
  unsigned short* Xb     = (unsigned short*)(ws + 35651584);  // [3][B*S*512] bf16 24 MB

  weight_prep<<<dim3(640), 256, 0, stream>>>(W_q, W_k, W_v, W_o, query, key, value,
                                             Wqt, Wkt, Wvt, Wot, Xb);

  proj128<<<dim3(64, 4, 3), 256, 0, stream>>>(Xb, Wqt, Wkt, Wvt,
                                              b_q, b_k, b_v, Qp, Kp, Vpt);

  attn_kernel<<<dim3(32, 16), 512, 0, stream>>>(Qp, Kp, Vpt, concat);

  gemm_out<<<dim3(128, 4), 256, 0, stream>>>(concat, Wot, b_o, out);
}

// Round 5
// 176.823 us; speedup vs baseline: 1.1696x; 1.0406x over previous
//
#include <hip/hip_runtime.h>
#include <hip/hip_bf16.h>

typedef __attribute__((ext_vector_type(8))) short bf16x8;
typedef __attribute__((ext_vector_type(4))) float f32x4;

#define SEQ 2048
#define DM  512
#define NH  8
#define DH  64
// (1/sqrt(2048)) * log2(e): folded into Q so scores come out ready for exp2
#define QSCALE 0.031879360f

__device__ __forceinline__ unsigned short f2bf(float f) {
  unsigned int u = __float_as_uint(f);
  unsigned int r = 0x7FFFu + ((u >> 16) & 1u);
  return (unsigned short)((u + r) >> 16);
}

// convert 2 float4 -> 8 bf16
__device__ __forceinline__ void cvt8f(const float4& v0, const float4& v1,
                                      unsigned short* __restrict__ o) {
  o[0] = f2bf(v0.x); o[1] = f2bf(v0.y); o[2] = f2bf(v0.z); o[3] = f2bf(v0.w);
  o[4] = f2bf(v1.x); o[5] = f2bf(v1.y); o[6] = f2bf(v1.z); o[7] = f2bf(v1.w);
}

// load 8 contiguous f32, convert to bf16
__device__ __forceinline__ void load8f(const float* __restrict__ s,
                                       unsigned short* __restrict__ o) {
  float4 v0 = *(const float4*)s;
  float4 v1 = *(const float4*)(s + 4);
  cvt8f(v0, v1, o);
}

// ---------- fused weight prep + X conversion ----------
// blocks [0,256): Wq/Wk/Wv per-head transpose + Wo transpose (f32->bf16)
// blocks [256,640): stream-convert query/key/value f32 -> bf16 into Xb[3][B*SEQ*DM]
__global__ __launch_bounds__(256) void weight_prep(const float* __restrict__ Wq,
                                                   const float* __restrict__ Wk,
                                                   const float* __restrict__ Wv,
                                                   const float* __restrict__ Wo,
                                                   const float* __restrict__ q,
                                                   const float* __restrict__ k,
                                                   const float* __restrict__ v,
                                                   unsigned short* __restrict__ Wqt,
                                                   unsigned short* __restrict__ Wkt,
                                                   unsigned short* __restrict__ Wvt,
                                                   unsigned short* __restrict__ Wot,
                                                   unsigned short* __restrict__ Xb) {
  const int tid = threadIdx.x;
  if (blockIdx.x >= 256) {
    const int wi = blockIdx.x - 256;                 // 0..383
    const float* src = (wi < 128) ? q : (wi < 256) ? k : v;
    const size_t off = (size_t)(wi & 127) * 32768;   // 128 blocks x 32768 = 4194304 elems/slice
    const float* s = src + off;
    unsigned short* d = Xb + (size_t)(wi >> 7) * (4u * SEQ * DM) + off;
#pragma unroll
    for (int i = 0; i < 16; ++i) {
      const size_t idx = (size_t)(tid + 256 * i) * 8;
      __align__(16) unsigned short t[8];
      load8f(s + idx, t);
      *(uint4*)(d + idx) = *(const uint4*)t;
    }
    return;
  }
  const int which = blockIdx.x >> 6, wi = blockIdx.x & 63;
  const float* src;
  unsigned short* dst;
  int R, C, r0, c0;
  if (which < 3) {
    const float* W = (which == 0) ? Wq : (which == 1) ? Wk : Wv;
    unsigned short* D = (which == 0) ? Wqt : (which == 1) ? Wkt : Wvt;
    int h = wi >> 3;
    src = W + (size_t)h * 512 * 64;
    dst = D + (size_t)h * 64 * 512;
    R = 512; C = 64; r0 = (wi & 7) * 64; c0 = 0;
  } else {
    src = Wo; dst = Wot;
    R = 512; C = 512; r0 = (wi >> 3) * 64; c0 = (wi & 7) * 64;
  }
  __shared__ __align__(16) unsigned short T[64][72];
#pragma unroll
  for (int i = 0; i < 2; ++i) {
    int c = tid + 256 * i;
    int lr = c >> 3, lc = (c & 7) * 8;
    __align__(16) unsigned short tmp[8];
    load8f(src + (size_t)(r0 + lr) * C + c0 + lc, tmp);
    *(uint4*)&T[lr][lc] = *(const uint4*)tmp;
  }
  __syncthreads();
#pragma unroll
  for (int i = 0; i < 2; ++i) {
    int c = tid + 256 * i;
    int orow = c >> 3, och = (c & 7) * 8;
    __align__(16) unsigned short tmp[8];
#pragma unroll
    for (int j = 0; j < 8; ++j) tmp[j] = T[och + j][orow];
    *(uint4*)(dst + (size_t)(c0 + orow) * R + r0 + och) = *(uint4*)tmp;
  }
}

// ---------- fused QKV projection, 128x128 tiles, pure-bf16 GEMM ----------
// z=0: Q (pre-scaled by QSCALE) -> Qp [B,H,S,64]; z=1: K -> Kp; z=2: V -> Vpt [B,H,64,S]
__global__ __launch_bounds__(256, 4) void proj128(const unsigned short* __restrict__ Xb,
                                                  const unsigned short* __restrict__ Wqt,
                                                  const unsigned short* __restrict__ Wkt,
                                                  const unsigned short* __restrict__ Wvt,
                                                  const float* __restrict__ bq,
                                                  const float* __restrict__ bk,
                                                  const float* __restrict__ bv,
                                                  unsigned short* __restrict__ Qp,
                                                  unsigned short* __restrict__ Kp,
                                                  unsigned short* __restrict__ Vpt) {
  const int which = blockIdx.z;
  const unsigned short* X = Xb + (size_t)which * (4u * SEQ * DM);
  const unsigned short* Wt = (which == 0) ? Wqt : (which == 1) ? Wkt : Wvt;  // [512n][512k]
  const float* bias = (which == 0) ? bq : (which == 1) ? bk : bv;
  unsigned short* out = (which == 0) ? Qp : (which == 1) ? Kp : Vpt;
  const float ps = (which == 0) ? QSCALE : 1.0f;

  const int m0 = blockIdx.x * 128;
  const int n0 = blockIdx.y * 128;
  __shared__ __align__(16) unsigned short smem[2][128][72];
  unsigned short (*As)[72] = smem[0];
  unsigned short (*Bs)[72] = smem[1];
  const int tid  = threadIdx.x;
  const int wave = tid >> 6, lane = tid & 63;
  const int l15  = lane & 15, quad = lane >> 4;
  const int rb = (wave >> 1) * 64, cb = (wave & 1) * 64;

  f32x4 acc[4][4];
#pragma unroll
  for (int i = 0; i < 4; ++i)
#pragma unroll
    for (int f = 0; f < 4; ++f) acc[i][f] = (f32x4){0.f, 0.f, 0.f, 0.f};

  for (int k0 = 0; k0 < DM; k0 += 64) {
    __syncthreads();
#pragma unroll
    for (int i = 0; i < 4; ++i) {
      int c = tid + 256 * i;             // 1024 slots x 8 elems = 128x64
      int lr = c >> 3, lc = (c & 7) * 8;
      *(uint4*)&As[lr][lc] = *(const uint4*)(X  + (size_t)(m0 + lr) * DM + k0 + lc);
      *(uint4*)&Bs[lr][lc] = *(const uint4*)(Wt + (size_t)(n0 + lr) * DM + k0 + lc);
    }
    __syncthreads();
#pragma unroll
    for (int kc = 0; kc < 2; ++kc) {
      bf16x8 av[4], bv4[4];
#pragma unroll
      for (int i = 0; i < 4; ++i) av[i]  = *(const bf16x8*)&As[rb + 16 * i + l15][kc * 32 + quad * 8];
#pragma unroll
      for (int f = 0; f < 4; ++f) bv4[f] = *(const bf16x8*)&Bs[cb + 16 * f + l15][kc * 32 + quad * 8];
#pragma unroll
      for (int i = 0; i < 4; ++i)
#pragma unroll
        for (int f = 0; f < 4; ++f)
          acc[i][f] = __builtin_amdgcn_mfma_f32_16x16x32_bf16(av[i], bv4[f], acc[i][f], 0, 0, 0);
    }
  }

  if (which < 2) {  // Q/K: [B,H,S,64]
#pragma unroll
    for (int i = 0; i < 4; ++i)
#pragma unroll
      for (int f = 0; f < 4; ++f)
#pragma unroll
        for (int r = 0; r < 4; ++r) {
          int m = m0 + rb + 16 * i + quad * 4 + r;
          int col = n0 + cb + 16 * f + l15;
          int head = col >> 6, o = col & 63;
          int b = m >> 11, s = m & (SEQ - 1);
          float val = (acc[i][f][r] + bias[col]) * ps;
          out[(((size_t)(b * NH + head) * SEQ + s) << 6) + o] = f2bf(val);
        }
  } else {  // V: emit V^T [B,H,64,S] via per-wave LDS bounce transpose
    __syncthreads();  // all waves done reading As/Bs
    unsigned short* T = &smem[0][0][0] + wave * 4608;  // [64][72] per wave
#pragma unroll
    for (int i = 0; i < 4; ++i)
#pragma unroll
      for (int f = 0; f < 4; ++f)
#pragma unroll
        for (int r = 0; r < 4; ++r) {
          int lrow = 16 * i + quad * 4 + r;   // seq-local
          int lcol = 16 * f + l15;            // dh-local
          int col = n0 + cb + 16 * f + l15;
          T[lcol * 72 + lrow] = f2bf(acc[i][f][r] + bias[col]);
        }
    const int mbase = m0 + rb;
    const int b = mbase >> 11, sbase = mbase & (SEQ - 1);
    const int head = (n0 + cb) >> 6;
    unsigned short* dstb = out + ((size_t)(b * NH + head) * DH) * SEQ + sbase;
#pragma unroll
    for (int j = 0; j < 8; ++j) {
      int dh = (lane >> 3) + j * 8;
      int sc = (lane & 7) * 8;
      *(uint4*)(dstb + (size_t)dh * SEQ + sc) = *(const uint4*)&T[dh * 72 + sc];
    }
  }
}

// ---------- flash attention, swapped-QK in-register softmax -> concat bf16 [B,SEQ,DM] ----------
// S^T = mfma(K_frag, Q_frag): lane (quad,l15) holds S^T[k=16f+4*quad+r][q=l15] -> the full
// P tile stays in registers. cvt_pk_bf16 packs pairs; a 2-instr permlane32/16_swap unzip
// network per u32 pair rebuilds the exact PV A-fragment. Removes per wave-iter: 16 b16
// LDS writes + 2 b128 LDS reads + the mid-iter lgkmcnt drain + ~40 f2bf VALU; frees the
// 19.5 KB Ps buffer (LDS pipe was ~60% of the wall at round 4).
__global__ __launch_bounds__(512, 4) void attn_kernel(const unsigned short* __restrict__ Qp,
                                                      const unsigned short* __restrict__ Kp,
                                                      const unsigned short* __restrict__ Vpt,
                                                      unsigned short* __restrict__ concat) {
  const int bh = blockIdx.x;            // 32: all blocks of one bh share an XCD (L2-resident K/V)
  const int ip = blockIdx.y;            // pair index 0..15
  const int b = bh >> 3, h = bh & 7;
  const int qa = ip, qb = 31 - ip;      // causal pairing: (qa+1)+(qb+1)=33 tiles/block, balanced
  __shared__ __align__(16) unsigned short Ks[2][64][72], Vts[2][64][72];
  const int tid  = threadIdx.x;
  const int wave = tid >> 6, lane = tid & 63;
  const int l15  = lane & 15, quad = lane >> 4;
  const int w4   = wave & 3;
  const bool isB = wave < 4;            // waves 0-3 -> qb, waves 4-7 -> qa
  const int qt   = isB ? qb : qa;
  const unsigned short* Qb = Qp  + (size_t)bh * SEQ * DH;
  const unsigned short* Kb = Kp  + (size_t)bh * SEQ * DH;
  const unsigned short* Vb = Vpt + (size_t)bh * DH * SEQ;

  // Q fragment (B-operand of the swapped MFMA -- identical lane map to the A-layout load)
  bf16x8 aq[2];
#pragma unroll
  for (int kc = 0; kc < 2; ++kc)
    aq[kc] = *(const bf16x8*)(Qb + (size_t)(qt * 64 + 16 * w4 + l15) * DH + kc * 32 + quad * 8);

  float l_acc = 0.f;     // partial row-sum for q-row l15 (this lane's 16 k-slots per tile)
  f32x4 Of[4];           // O[q_local = quad*4+r][v = 16f+l15]
#pragma unroll
  for (int f = 0; f < 4; ++f) Of[f] = (f32x4){0.f, 0.f, 0.f, 0.f};

  // staging: K tile 64x64 bf16 = 512 uint4 chunks; 512 threads own 1 chunk each (K and V)
  const int sr = tid >> 3, sc = (tid & 7) * 8;
  uint4 kst, vst;

#define STAGE_LOAD(lt_) do {                                                   \
    kst = *(const uint4*)(Kb + (size_t)((lt_) * 64 + sr) * DH + sc);           \
    vst = *(const uint4*)(Vb + (size_t)sr * SEQ + (lt_) * 64 + sc);            \
  } while (0)

#define STAGE_WRITE(bi_) do {                                                  \
    *(uint4*)&Ks[bi_][sr][sc]  = kst;                                          \
    *(uint4*)&Vts[bi_][sr][sc] = vst;                                          \
  } while (0)

#define CVTPK(d_, lo_, hi_) asm("v_cvt_pk_bf16_f32 %0, %1, %2" : "=v"(d_) : "v"(lo_), "v"(hi_))
#define PL32SWAP(a_, b_) asm("v_permlane32_swap_b32 %0, %1" : "+v"(a_), "+v"(b_))
#define PL16SWAP(a_, b_) asm("v_permlane16_swap_b32 %0, %1" : "+v"(a_), "+v"(b_))

  // prologue: tile 0 -> buf 0; tile 1 -> regs (qb >= 16 so tiles 0,1 always exist)
  STAGE_LOAD(0);
  STAGE_WRITE(0);
  STAGE_LOAD(1);
  __syncthreads();

#pragma unroll 1
  for (int lt = 0; lt <= qb; ++lt) {
    const int cur = lt & 1;
    if (lt < qb) STAGE_WRITE(cur ^ 1);       // tile lt+1 into other buffer
    if (lt + 2 <= qb) STAGE_LOAD(lt + 2);    // issue tile lt+2 loads under this iter

    const bool act = isB || (lt <= qa);
    if (act) {
      // S^T = K (Q*QSCALE)^T  (log2e folded into Q)
      f32x4 S[4];
#pragma unroll
      for (int f = 0; f < 4; ++f) S[f] = (f32x4){0.f, 0.f, 0.f, 0.f};
#pragma unroll
      for (int kc = 0; kc < 2; ++kc) {
#pragma unroll
        for (int f = 0; f < 4; ++f) {
          bf16x8 bk = *(const bf16x8*)&Ks[cur][16 * f + l15][kc * 32 + quad * 8];
          S[f] = __builtin_amdgcn_mfma_f32_16x16x32_bf16(bk, aq[kc], S[f], 0, 0, 0);
        }
      }
      if (lt == qt) {   // causal mask: k_local > q_local
        const int qloc = 16 * w4 + l15;
#pragma unroll
        for (int f = 0; f < 4; ++f)
#pragma unroll
          for (int r = 0; r < 4; ++r)
            if (16 * f + 4 * quad + r > qloc) S[f][r] = -1e30f;
      }
      // p = exp2(S'), pack to bf16 pairs in-register
      unsigned int P0[4], P1[4];
#pragma unroll
      for (int f = 0; f < 4; ++f) {
        float p0 = __builtin_amdgcn_exp2f(S[f][0]);
        float p1 = __builtin_amdgcn_exp2f(S[f][1]);
        float p2 = __builtin_amdgcn_exp2f(S[f][2]);
        float p3 = __builtin_amdgcn_exp2f(S[f][3]);
        l_acc += (p0 + p1) + (p2 + p3);
        CVTPK(P0[f], p0, p1);
        CVTPK(P1[f], p2, p3);
      }
      // redistribute to PV A-fragment: per kc, unzip ([u0,u1,u2,u3],[v0,v1,v2,v3]) ->
      // ([u0,u2,v0,v2],[u1,u3,v1,v3]) via permlane32_swap + permlane16_swap
#pragma unroll
      for (int kc = 0; kc < 2; ++kc) {
        unsigned int x0 = P0[2 * kc], y0 = P0[2 * kc + 1];
        unsigned int x1 = P1[2 * kc], y1 = P1[2 * kc + 1];
        PL32SWAP(x0, y0); PL16SWAP(x0, y0);
        PL32SWAP(x1, y1); PL16SWAP(x1, y1);
        union { unsigned int u[4]; bf16x8 v; } ap;
        ap.u[0] = x0; ap.u[1] = x1; ap.u[2] = y0; ap.u[3] = y1;
#pragma unroll
        for (int f = 0; f < 4; ++f) {
          bf16x8 bvv = *(const bf16x8*)&Vts[cur][16 * f + l15][kc * 32 + quad * 8];
          Of[f] = __builtin_amdgcn_mfma_f32_16x16x32_bf16(ap.v, bvv, Of[f], 0, 0, 0);
        }
      }
    }
    __syncthreads();
  }
#undef STAGE_LOAD
#undef STAGE_WRITE
#undef CVTPK
#undef PL32SWAP
#undef PL16SWAP

  // L[q=l15] = sum over the 4 quads; then fetch L[quad*4+r] per lane for the epilogue
  l_acc += __shfl_xor(l_acc, 16);
  l_acc += __shfl_xor(l_acc, 32);
  float rl[4];
#pragma unroll
  for (int r = 0; r < 4; ++r) rl[r] = 1.0f / __shfl(l_acc, quad * 4 + r);

#pragma unroll
  for (int f = 0; f < 4; ++f)
#pragma unroll
    for (int r = 0; r < 4; ++r) {
      const int row = qt * 64 + 16 * w4 + quad * 4 + r;
      const int col = h * DH + 16 * f + l15;
      concat[(size_t)(b * SEQ + row) * DM + col] = f2bf(Of[f][r] * rl[r]);
    }
}

// ---------- output projection: out_f32 = concat_bf16 @ Wot^T + b_o ----------
__global__ __launch_bounds__(256, 2) void gemm_out(const unsigned short* __restrict__ A,
                                                   const unsigned short* __restrict__ Bt,
                                                   const float* __restrict__ bias,
                                                   float* __restrict__ out) {
  const int m0 = blockIdx.x * 64;
  const int nbase = blockIdx.y * 128;
  __shared__ __align__(16) unsigned short Bs[2][64][72];
  const int tid  = threadIdx.x;
  const int wave = tid >> 6, lane = tid & 63;
  const int l15  = lane & 15, quad = lane >> 4;

  bf16x8 afr[16];  // per-wave A rows held in registers across all steps
  const unsigned short* arow = A + (size_t)(m0 + 16 * wave + l15) * DM;
#pragma unroll
  for (int k0i = 0; k0i < 8; ++k0i)
#pragma unroll
    for (int kc = 0; kc < 2; ++kc)
      afr[k0i * 2 + kc] = *(const bf16x8*)(arow + k0i * 64 + kc * 32 + quad * 8);

  uint4 bst0, bst1;
  const int br = tid >> 3, bc = (tid & 7) * 8;

#define G_LOAD(s_) do {                                                          \
    const int n0_ = nbase + ((s_) >> 3) * 64, k0_ = ((s_) & 7) * 64;             \
    bst0 = *(const uint4*)(Bt + (size_t)(n0_ + br) * DM + k0_ + bc);             \
    bst1 = *(const uint4*)(Bt + (size_t)(n0_ + br + 32) * DM + k0_ + bc);        \
  } while (0)

#define G_WRITE(bi_) do {                                                        \
    *(uint4*)&Bs[bi_][br][bc]      = bst0;                                       \
    *(uint4*)&Bs[bi_][br + 32][bc] = bst1;                                       \
  } while (0)

  f32x4 acc[2][4];
#pragma unroll
  for (int nh = 0; nh < 2; ++nh)
#pragma unroll
    for (int f = 0; f < 4; ++f) acc[nh][f] = (f32x4){0.f, 0.f, 0.f, 0.f};

  G_LOAD(0);
  G_WRITE(0);
  G_LOAD(1);
  __syncthreads();

#pragma unroll
  for (int s = 0; s < 16; ++s) {   // full unroll: s, nh, cur all compile-time
    const int cur = s & 1;
    if (s < 15) G_WRITE(cur ^ 1);
    if (s < 14) G_LOAD(s + 2);
    const int nh = s >> 3, k0i = s & 7;
#pragma unroll
    for (int kc = 0; kc < 2; ++kc)
#pragma unroll
      for (int f = 0; f < 4; ++f) {
        bf16x8 bfv = *(const bf16x8*)&Bs[cur][16 * f + l15][kc * 32 + quad * 8];
        acc[nh][f] = __builtin_amdgcn_mfma_f32_16x16x32_bf16(afr[k0i * 2 + kc], bfv, acc[nh][f], 0, 0, 0);
      }
    __syncthreads();
  }
#undef G_LOAD
#undef G_WRITE

#pragma unroll
  for (int nh = 0; nh < 2; ++nh)
#pragma unroll
    for (int f = 0; f < 4; ++f)
#pragma unroll
      for (int r = 0; r < 4; ++r) {
        int row = 16 * wave + quad * 4 + r;
        int col = nbase + nh * 64 + 16 * f + l15;
        out[(size_t)(m0 + row) * DM + col] = acc[nh][f][r] + bias[col];
      }
}

extern "C" void kernel_launch(void* const* d_in, const int* in_sizes, int n_in,
                              void* d_out, int out_size, void* d_ws, size_t ws_size,
                              hipStream_t stream) {
  const float* query = (const float*)d_in[0];
  const float* key   = (const float*)d_in[1];
  const float* value = (const float*)d_in[2];
  const float* W_q   = (const float*)d_in[3];
  const float* b_q   = (const float*)d_in[4];
  const float* W_k   = (const float*)d_in[5];
  const float* b_k   = (const float*)d_in[6];
  const float* W_v   = (const float*)d_in[7];
  const float* b_v   = (const float*)d_in[8];
  const float* W_o   = (const float*)d_in[9];
  const float* b_o   = (const float*)d_in[10];
  float* out = (float*)d_out;

  char* ws = (char*)d_ws;
  unsigned short* Wqt    = (unsigned short*)(ws + 0);         // [H][64][512] bf16
  unsigned short* Wkt    = (unsigned short*)(ws + 524288);
  unsigned short* Wvt    = (unsigned short*)(ws + 1048576);
  unsigned short* Wot    = (unsigned short*)(ws + 1572864);   // [512][512] bf16
  unsigned short* Qp     = (unsigned short*)(ws + 2097152);   // [B,H,S,64] bf16 8 MB
  unsigned short* Kp     = (unsigned short*)(ws + 10485760);
  unsigned short* Vpt    = (unsigned short*)(ws + 18874368);  // [B,H,64,S] bf16 8 MB
  unsigned short* concat = (unsigned short*)(ws + 27262976);  // [B,S,512] bf16 8 MB
  unsigned short* Xb     = (unsigned short*)(ws + 35651584);  // [3][B*S*512] bf16 24 MB

  weight_prep<<<dim3(640), 256, 0, stream>>>(W_q, W_k, W_v, W_o, query, key, value,
                                             Wqt, Wkt, Wvt, Wot, Xb);

  proj128<<<dim3(64, 4, 3), 256, 0, stream>>>(Xb, Wqt, Wkt, Wvt,
                                              b_q, b_k, b_v, Qp, Kp, Vpt);

  attn_kernel<<<dim3(32, 16), 512, 0, stream>>>(Qp, Kp, Vpt, concat);

  gemm_out<<<dim3(128, 4), 256, 0, stream>>>(concat, Wot, b_o, out);
}

// Round 6
// 173.042 us; speedup vs baseline: 1.1952x; 1.0218x over previous
//
#include <hip/hip_runtime.h>
#include <hip/hip_bf16.h>

typedef __attribute__((ext_vector_type(8))) short bf16x8;
typedef __attribute__((ext_vector_type(4))) float f32x4;

#define SEQ 2048
#define DM  512
#define NH  8
#define DH  64
// (1/sqrt(2048)) * log2(e): folded into Q so scores come out ready for exp2
#define QSCALE 0.031879360f

__device__ __forceinline__ unsigned short f2bf(float f) {
  unsigned int u = __float_as_uint(f);
  unsigned int r = 0x7FFFu + ((u >> 16) & 1u);
  return (unsigned short)((u + r) >> 16);
}

// convert 2 float4 -> 8 bf16
__device__ __forceinline__ void cvt8f(const float4& v0, const float4& v1,
                                      unsigned short* __restrict__ o) {
  o[0] = f2bf(v0.x); o[1] = f2bf(v0.y); o[2] = f2bf(v0.z); o[3] = f2bf(v0.w);
  o[4] = f2bf(v1.x); o[5] = f2bf(v1.y); o[6] = f2bf(v1.z); o[7] = f2bf(v1.w);
}

// load 8 contiguous f32, convert to bf16
__device__ __forceinline__ void load8f(const float* __restrict__ s,
                                       unsigned short* __restrict__ o) {
  float4 v0 = *(const float4*)s;
  float4 v1 = *(const float4*)(s + 4);
  cvt8f(v0, v1, o);
}

// async global->LDS DMA, 16B per lane (dest = wave-uniform base + lane*16)
__device__ __forceinline__ void gload16(const unsigned short* g, unsigned short* l) {
  __builtin_amdgcn_global_load_lds(
      (const __attribute__((address_space(1))) void*)g,
      (__attribute__((address_space(3))) void*)l, 16, 0, 0);
}

// ---------- fused weight prep + X conversion ----------
// blocks [0,256): Wq/Wk/Wv per-head transpose + Wo transpose (f32->bf16)
// blocks [256,640): stream-convert query/key/value f32 -> bf16 into Xb[3][B*SEQ*DM]
__global__ __launch_bounds__(256) void weight_prep(const float* __restrict__ Wq,
                                                   const float* __restrict__ Wk,
                                                   const float* __restrict__ Wv,
                                                   const float* __restrict__ Wo,
                                                   const float* __restrict__ q,
                                                   const float* __restrict__ k,
                                                   const float* __restrict__ v,
                                                   unsigned short* __restrict__ Wqt,
                                                   unsigned short* __restrict__ Wkt,
                                                   unsigned short* __restrict__ Wvt,
                                                   unsigned short* __restrict__ Wot,
                                                   unsigned short* __restrict__ Xb) {
  const int tid = threadIdx.x;
  if (blockIdx.x >= 256) {
    const int wi = blockIdx.x - 256;                 // 0..383
    const float* src = (wi < 128) ? q : (wi < 256) ? k : v;
    const size_t off = (size_t)(wi & 127) * 32768;   // 128 blocks x 32768 = 4194304 elems/slice
    const float* s = src + off;
    unsigned short* d = Xb + (size_t)(wi >> 7) * (4u * SEQ * DM) + off;
#pragma unroll
    for (int i = 0; i < 16; ++i) {
      const size_t idx = (size_t)(tid + 256 * i) * 8;
      __align__(16) unsigned short t[8];
      load8f(s + idx, t);
      *(uint4*)(d + idx) = *(const uint4*)t;
    }
    return;
  }
  const int which = blockIdx.x >> 6, wi = blockIdx.x & 63;
  const float* src;
  unsigned short* dst;
  int R, C, r0, c0;
  if (which < 3) {
    const float* W = (which == 0) ? Wq : (which == 1) ? Wk : Wv;
    unsigned short* D = (which == 0) ? Wqt : (which == 1) ? Wkt : Wvt;
    int h = wi >> 3;
    src = W + (size_t)h * 512 * 64;
    dst = D + (size_t)h * 64 * 512;
    R = 512; C = 64; r0 = (wi & 7) * 64; c0 = 0;
  } else {
    src = Wo; dst = Wot;
    R = 512; C = 512; r0 = (wi >> 3) * 64; c0 = (wi & 7) * 64;
  }
  __shared__ __align__(16) unsigned short T[64][72];
#pragma unroll
  for (int i = 0; i < 2; ++i) {
    int c = tid + 256 * i;
    int lr = c >> 3, lc = (c & 7) * 8;
    __align__(16) unsigned short tmp[8];
    load8f(src + (size_t)(r0 + lr) * C + c0 + lc, tmp);
    *(uint4*)&T[lr][lc] = *(const uint4*)tmp;
  }
  __syncthreads();
#pragma unroll
  for (int i = 0; i < 2; ++i) {
    int c = tid + 256 * i;
    int orow = c >> 3, och = (c & 7) * 8;
    __align__(16) unsigned short tmp[8];
#pragma unroll
    for (int j = 0; j < 8; ++j) tmp[j] = T[och + j][orow];
    *(uint4*)(dst + (size_t)(c0 + orow) * R + r0 + och) = *(uint4*)tmp;
  }
}

// ---------- fused QKV projection, 128x128 tiles, global_load_lds staging ----------
// z=0: Q (pre-scaled by QSCALE) -> Qp [B,H,S,64]; z=1: K -> Kp; z=2: V -> Vpt [B,H,64,S]
// m97 2-barrier structure + async DMA staging: LDS dest is LINEAR [128][64] (gload_lds
// can't scatter); the per-lane GLOBAL source carries the inverse XOR swizzle
// (colgrp = (lane&7)^(lane>>3), within one 128B row segment -> coalescing intact);
// fragment reads apply the same XOR (c16 = (kc*4+quad)^(row&7)) -> 2-way banks (free).
__global__ __launch_bounds__(256, 4) void proj128(const unsigned short* __restrict__ Xb,
                                                  const unsigned short* __restrict__ Wqt,
                                                  const unsigned short* __restrict__ Wkt,
                                                  const unsigned short* __restrict__ Wvt,
                                                  const float* __restrict__ bq,
                                                  const float* __restrict__ bk,
                                                  const float* __restrict__ bv,
                                                  unsigned short* __restrict__ Qp,
                                                  unsigned short* __restrict__ Kp,
                                                  unsigned short* __restrict__ Vpt) {
  const int which = blockIdx.z;
  const unsigned short* X = Xb + (size_t)which * (4u * SEQ * DM);
  const unsigned short* Wt = (which == 0) ? Wqt : (which == 1) ? Wkt : Wvt;  // [512n][512k]
  const float* bias = (which == 0) ? bq : (which == 1) ? bk : bv;
  unsigned short* out = (which == 0) ? Qp : (which == 1) ? Kp : Vpt;
  const float ps = (which == 0) ? QSCALE : 1.0f;

  const int m0 = blockIdx.x * 128;
  const int n0 = blockIdx.y * 128;
  // A[128][64] @0, B[128][64] @8192 (shorts); epilogue reuses as 4x per-wave [64][72]
  __shared__ __align__(16) unsigned short smem[18432];
  const int tid  = threadIdx.x;
  const int wave = tid >> 6, lane = tid & 63;
  const int l15  = lane & 15, quad = lane >> 4;
  const int rb = (wave >> 1) * 64, cb = (wave & 1) * 64;

  // staging geometry: issue i covers rows [i*32, i*32+32); this lane owns
  // (row = i*32 + wave*8 + lane>>3, LDS colgrp = lane&7) <- global colgrp ^ (row&7)
  const int srow = wave * 8 + (lane >> 3);
  const int g8   = (((lane & 7) ^ (lane >> 3)) << 3);
  const unsigned short* aSrc = X  + (size_t)(m0 + srow) * DM + g8;
  const unsigned short* bSrc = Wt + (size_t)(n0 + srow) * DM + g8;
  unsigned short* aDst = smem        + wave * 512 + lane * 8;
  unsigned short* bDst = smem + 8192 + wave * 512 + lane * 8;

  f32x4 acc[4][4];
#pragma unroll
  for (int i = 0; i < 4; ++i)
#pragma unroll
    for (int f = 0; f < 4; ++f) acc[i][f] = (f32x4){0.f, 0.f, 0.f, 0.f};

  for (int k0 = 0; k0 < DM; k0 += 64) {
    __syncthreads();              // previous tile's readers done
#pragma unroll
    for (int i = 0; i < 4; ++i) {
      gload16(aSrc + (size_t)(i * 32) * DM + k0, aDst + i * 2048);
      gload16(bSrc + (size_t)(i * 32) * DM + k0, bDst + i * 2048);
    }
    __syncthreads();              // drains vmcnt(0): DMA landed
#pragma unroll
    for (int kc = 0; kc < 2; ++kc) {
      bf16x8 av[4], bv4[4];
#pragma unroll
      for (int i = 0; i < 4; ++i)
        av[i]  = *(const bf16x8*)(smem + (size_t)(rb + 16 * i + l15) * 64 +
                                  (((kc * 4 + quad) ^ (l15 & 7)) << 3));
#pragma unroll
      for (int f = 0; f < 4; ++f)
        bv4[f] = *(const bf16x8*)(smem + 8192 + (size_t)(cb + 16 * f + l15) * 64 +
                                  (((kc * 4 + quad) ^ (l15 & 7)) << 3));
#pragma unroll
      for (int i = 0; i < 4; ++i)
#pragma unroll
        for (int f = 0; f < 4; ++f)
          acc[i][f] = __builtin_amdgcn_mfma_f32_16x16x32_bf16(av[i], bv4[f], acc[i][f], 0, 0, 0);
    }
  }

  if (which < 2) {  // Q/K: [B,H,S,64]
#pragma unroll
    for (int i = 0; i < 4; ++i)
#pragma unroll
      for (int f = 0; f < 4; ++f)
#pragma unroll
        for (int r = 0; r < 4; ++r) {
          int m = m0 + rb + 16 * i + quad * 4 + r;
          int col = n0 + cb + 16 * f + l15;
          int head = col >> 6, o = col & 63;
          int b = m >> 11, s = m & (SEQ - 1);
          float val = (acc[i][f][r] + bias[col]) * ps;
          out[(((size_t)(b * NH + head) * SEQ + s) << 6) + o] = f2bf(val);
        }
  } else {  // V: emit V^T [B,H,64,S] via per-wave LDS bounce transpose
    __syncthreads();  // all waves done reading A/B tiles
    unsigned short* T = smem + wave * 4608;  // [64][72] per wave
#pragma unroll
    for (int i = 0; i < 4; ++i)
#pragma unroll
      for (int f = 0; f < 4; ++f)
#pragma unroll
        for (int r = 0; r < 4; ++r) {
          int lrow = 16 * i + quad * 4 + r;   // seq-local
          int lcol = 16 * f + l15;            // dh-local
          int col = n0 + cb + 16 * f + l15;
          T[lcol * 72 + lrow] = f2bf(acc[i][f][r] + bias[col]);
        }
    const int mbase = m0 + rb;
    const int b = mbase >> 11, sbase = mbase & (SEQ - 1);
    const int head = (n0 + cb) >> 6;
    unsigned short* dstb = out + ((size_t)(b * NH + head) * DH) * SEQ + sbase;
#pragma unroll
    for (int j = 0; j < 8; ++j) {
      int dh = (lane >> 3) + j * 8;
      int sc = (lane & 7) * 8;
      *(uint4*)(dstb + (size_t)dh * SEQ + sc) = *(const uint4*)&T[dh * 72 + sc];
    }
  }
}

// ---------- flash attention, swapped-QK in-register softmax -> concat bf16 [B,SEQ,DM] ----------
// S^T = mfma(K_frag, Q_frag): lane (quad,l15) holds S^T[k=16f+4*quad+r][q=l15] -> the full
// P tile stays in registers. cvt_pk_bf16 packs pairs; a 2-instr permlane32/16_swap unzip
// network per u32 pair rebuilds the exact PV A-fragment.
__global__ __launch_bounds__(512, 4) void attn_kernel(const unsigned short* __restrict__ Qp,
                                                      const unsigned short* __restrict__ Kp,
                                                      const unsigned short* __restrict__ Vpt,
                                                      unsigned short* __restrict__ concat) {
  const int bh = blockIdx.x;            // 32: all blocks of one bh share an XCD (L2-resident K/V)
  const int ip = blockIdx.y;            // pair index 0..15
  const int b = bh >> 3, h = bh & 7;
  const int qa = ip, qb = 31 - ip;      // causal pairing: (qa+1)+(qb+1)=33 tiles/block, balanced
  __shared__ __align__(16) unsigned short Ks[2][64][72], Vts[2][64][72];
  const int tid  = threadIdx.x;
  const int wave = tid >> 6, lane = tid & 63;
  const int l15  = lane & 15, quad = lane >> 4;
  const int w4   = wave & 3;
  const bool isB = wave < 4;            // waves 0-3 -> qb, waves 4-7 -> qa
  const int qt   = isB ? qb : qa;
  const unsigned short* Qb = Qp  + (size_t)bh * SEQ * DH;
  const unsigned short* Kb = Kp  + (size_t)bh * SEQ * DH;
  const unsigned short* Vb = Vpt + (size_t)bh * DH * SEQ;

  // Q fragment (B-operand of the swapped MFMA -- identical lane map to the A-layout load)
  bf16x8 aq[2];
#pragma unroll
  for (int kc = 0; kc < 2; ++kc)
    aq[kc] = *(const bf16x8*)(Qb + (size_t)(qt * 64 + 16 * w4 + l15) * DH + kc * 32 + quad * 8);

  float l_acc = 0.f;     // partial row-sum for q-row l15 (this lane's 16 k-slots per tile)
  f32x4 Of[4];           // O[q_local = quad*4+r][v = 16f+l15]
#pragma unroll
  for (int f = 0; f < 4; ++f) Of[f] = (f32x4){0.f, 0.f, 0.f, 0.f};

  // staging: K tile 64x64 bf16 = 512 uint4 chunks; 512 threads own 1 chunk each (K and V)
  const int sr = tid >> 3, sc = (tid & 7) * 8;
  uint4 kst, vst;

#define STAGE_LOAD(lt_) do {                                                   \
    kst = *(const uint4*)(Kb + (size_t)((lt_) * 64 + sr) * DH + sc);           \
    vst = *(const uint4*)(Vb + (size_t)sr * SEQ + (lt_) * 64 + sc);            \
  } while (0)

#define STAGE_WRITE(bi_) do {                                                  \
    *(uint4*)&Ks[bi_][sr][sc]  = kst;                                          \
    *(uint4*)&Vts[bi_][sr][sc] = vst;                                          \
  } while (0)

#define CVTPK(d_, lo_, hi_) asm("v_cvt_pk_bf16_f32 %0, %1, %2" : "=v"(d_) : "v"(lo_), "v"(hi_))
#define PL32SWAP(a_, b_) asm("v_permlane32_swap_b32 %0, %1" : "+v"(a_), "+v"(b_))
#define PL16SWAP(a_, b_) asm("v_permlane16_swap_b32 %0, %1" : "+v"(a_), "+v"(b_))

  // prologue: tile 0 -> buf 0; tile 1 -> regs (qb >= 16 so tiles 0,1 always exist)
  STAGE_LOAD(0);
  STAGE_WRITE(0);
  STAGE_LOAD(1);
  __syncthreads();

#pragma unroll 1
  for (int lt = 0; lt <= qb; ++lt) {
    const int cur = lt & 1;
    if (lt < qb) STAGE_WRITE(cur ^ 1);       // tile lt+1 into other buffer
    if (lt + 2 <= qb) STAGE_LOAD(lt + 2);    // issue tile lt+2 loads under this iter

    const bool act = isB || (lt <= qa);
    if (act) {
      // S^T = K (Q*QSCALE)^T  (log2e folded into Q)
      f32x4 S[4];
#pragma unroll
      for (int f = 0; f < 4; ++f) S[f] = (f32x4){0.f, 0.f, 0.f, 0.f};
#pragma unroll
      for (int kc = 0; kc < 2; ++kc) {
#pragma unroll
        for (int f = 0; f < 4; ++f) {
          bf16x8 bk = *(const bf16x8*)&Ks[cur][16 * f + l15][kc * 32 + quad * 8];
          S[f] = __builtin_amdgcn_mfma_f32_16x16x32_bf16(bk, aq[kc], S[f], 0, 0, 0);
        }
      }
      if (lt == qt) {   // causal mask: k_local > q_local
        const int qloc = 16 * w4 + l15;
#pragma unroll
        for (int f = 0; f < 4; ++f)
#pragma unroll
          for (int r = 0; r < 4; ++r)
            if (16 * f + 4 * quad + r > qloc) S[f][r] = -1e30f;
      }
      // p = exp2(S'), pack to bf16 pairs in-register
      unsigned int P0[4], P1[4];
#pragma unroll
      for (int f = 0; f < 4; ++f) {
        float p0 = __builtin_amdgcn_exp2f(S[f][0]);
        float p1 = __builtin_amdgcn_exp2f(S[f][1]);
        float p2 = __builtin_amdgcn_exp2f(S[f][2]);
        float p3 = __builtin_amdgcn_exp2f(S[f][3]);
        l_acc += (p0 + p1) + (p2 + p3);
        CVTPK(P0[f], p0, p1);
        CVTPK(P1[f], p2, p3);
      }
      // redistribute to PV A-fragment: per kc, unzip ([u0,u1,u2,u3],[v0,v1,v2,v3]) ->
      // ([u0,u2,v0,v2],[u1,u3,v1,v3]) via permlane32_swap + permlane16_swap
#pragma unroll
      for (int kc = 0; kc < 2; ++kc) {
        unsigned int x0 = P0[2 * kc], y0 = P0[2 * kc + 1];
        unsigned int x1 = P1[2 * kc], y1 = P1[2 * kc + 1];
        PL32SWAP(x0, y0); PL16SWAP(x0, y0);
        PL32SWAP(x1, y1); PL16SWAP(x1, y1);
        union { unsigned int u[4]; bf16x8 v; } ap;
        ap.u[0] = x0; ap.u[1] = x1; ap.u[2] = y0; ap.u[3] = y1;
#pragma unroll
        for (int f = 0; f < 4; ++f) {
          bf16x8 bvv = *(const bf16x8*)&Vts[cur][16 * f + l15][kc * 32 + quad * 8];
          Of[f] = __builtin_amdgcn_mfma_f32_16x16x32_bf16(ap.v, bvv, Of[f], 0, 0, 0);
        }
      }
    }
    __syncthreads();
  }
#undef STAGE_LOAD
#undef STAGE_WRITE
#undef CVTPK
#undef PL32SWAP
#undef PL16SWAP

  // L[q=l15] = sum over the 4 quads; then fetch L[quad*4+r] per lane for the epilogue
  l_acc += __shfl_xor(l_acc, 16);
  l_acc += __shfl_xor(l_acc, 32);
  float rl[4];
#pragma unroll
  for (int r = 0; r < 4; ++r) rl[r] = 1.0f / __shfl(l_acc, quad * 4 + r);

#pragma unroll
  for (int f = 0; f < 4; ++f)
#pragma unroll
    for (int r = 0; r < 4; ++r) {
      const int row = qt * 64 + 16 * w4 + quad * 4 + r;
      const int col = h * DH + 16 * f + l15;
      concat[(size_t)(b * SEQ + row) * DM + col] = f2bf(Of[f][r] * rl[r]);
    }
}

// ---------- output projection: out_f32 = concat_bf16 @ Wot^T + b_o ----------
// 1-barrier dbuf with global_load_lds B staging (linear LDS dest, inverse-swizzled
// global source, XOR-swizzled fragment reads). 16 fully-unrolled (n0,k0) steps.
__global__ __launch_bounds__(256, 2) void gemm_out(const unsigned short* __restrict__ A,
                                                   const unsigned short* __restrict__ Bt,
                                                   const float* __restrict__ bias,
                                                   float* __restrict__ out) {
  const int m0 = blockIdx.x * 64;
  const int nbase = blockIdx.y * 128;
  __shared__ __align__(16) unsigned short Bs[2][64][64];   // 16 KB
  const int tid  = threadIdx.x;
  const int wave = tid >> 6, lane = tid & 63;
  const int l15  = lane & 15, quad = lane >> 4;

  bf16x8 afr[16];  // per-wave A rows held in registers across all steps
  const unsigned short* arow = A + (size_t)(m0 + 16 * wave + l15) * DM;
#pragma unroll
  for (int k0i = 0; k0i < 8; ++k0i)
#pragma unroll
    for (int kc = 0; kc < 2; ++kc)
      afr[k0i * 2 + kc] = *(const bf16x8*)(arow + k0i * 64 + kc * 32 + quad * 8);

  const int srow = wave * 8 + (lane >> 3);
  const int g8   = (((lane & 7) ^ (lane >> 3)) << 3);
  unsigned short* bDst = &Bs[0][0][0] + wave * 512 + lane * 8;

#define G_STAGE(s_, bi_) do {                                                    \
    const int n0_ = nbase + ((s_) >> 3) * 64, k0_ = ((s_) & 7) * 64;             \
    _Pragma("unroll")                                                            \
    for (int i_ = 0; i_ < 2; ++i_)                                               \
      gload16(Bt + (size_t)(n0_ + i_ * 32 + srow) * DM + k0_ + g8,               \
              bDst + (bi_) * 4096 + i_ * 2048);                                  \
  } while (0)

  f32x4 acc[2][4];
#pragma unroll
  for (int nh = 0; nh < 2; ++nh)
#pragma unroll
    for (int f = 0; f < 4; ++f) acc[nh][f] = (f32x4){0.f, 0.f, 0.f, 0.f};

  G_STAGE(0, 0);
  __syncthreads();

#pragma unroll
  for (int s = 0; s < 16; ++s) {   // full unroll: s, nh, cur all compile-time
    const int cur = s & 1;
    if (s < 15) G_STAGE(s + 1, cur ^ 1);
    const int nh = s >> 3;
#pragma unroll
    for (int kc = 0; kc < 2; ++kc)
#pragma unroll
      for (int f = 0; f < 4; ++f) {
        bf16x8 bfv = *(const bf16x8*)(&Bs[cur][0][0] + (size_t)(16 * f + l15) * 64 +
                                      (((kc * 4 + quad) ^ (l15 & 7)) << 3));
        acc[nh][f] = __builtin_amdgcn_mfma_f32_16x16x32_bf16(afr[(s & 7) * 2 + kc], bfv, acc[nh][f], 0, 0, 0);
      }
    __syncthreads();   // drains vmcnt: next buffer staged; readers of cur done
  }
#undef G_STAGE

#pragma unroll
  for (int nh = 0; nh < 2; ++nh)
#pragma unroll
    for (int f = 0; f < 4; ++f)
#pragma unroll
      for (int r = 0; r < 4; ++r) {
        int row = 16 * wave + quad * 4 + r;
        int col = nbase + nh * 64 + 16 * f + l15;
        out[(size_t)(m0 + row) * DM + col] = acc[nh][f][r] + bias[col];
      }
}

extern "C" void kernel_launch(void* const* d_in, const int* in_sizes, int n_in,
                              void* d_out, int out_size, void* d_ws, size_t ws_size,
                              hipStream_t stream) {
  const float* query = (const float*)d_in[0];
  const float* key   = (const float*)d_in[1];
  const float* value = (const float*)d_in[2];
  const float* W_q   = (const float*)d_in[3];
  const float* b_q   = (const float*)d_in[4];
  const float* W_k   = (const float*)d_in[5];
  const float* b_k   = (const float*)d_in[6];
  const float* W_v   = (const float*)d_in[7];
  const float* b_v   = (const float*)d_in[8];
  const float* W_o   = (const float*)d_in[9];
  const float* b_o   = (const float*)d_in[10];
  float* out = (float*)d_out;

  char* ws = (char*)d_ws;
  unsigned short* Wqt    = (unsigned short*)(ws + 0);         // [H][64][512] bf16
  unsigned short* Wkt    = (unsigned short*)(ws + 524288);
  unsigned short* Wvt    = (unsigned short*)(ws + 1048576);
  unsigned short* Wot    = (unsigned short*)(ws + 1572864);   // [512][512] bf16
  unsigned short* Qp     = (unsigned short*)(ws + 2097152);   // [B,H,S,64] bf16 8 MB
  unsigned short* Kp     = (unsigned short*)(ws + 10485760);
  unsigned short* Vpt    = (unsigned short*)(ws + 18874368);  // [B,H,64,S] bf16 8 MB
  unsigned short* concat = (unsigned short*)(ws + 27262976);  // [B,S,512] bf16 8 MB
  unsigned short* Xb     = (unsigned short*)(ws + 35651584);  // [3][B*S*512] bf16 24 MB

  weight_prep<<<dim3(640), 256, 0, stream>>>(W_q, W_k, W_v, W_o, query, key, value,
                                             Wqt, Wkt, Wvt, Wot, Xb);

  proj128<<<dim3(64, 4, 3), 256, 0, stream>>>(Xb, Wqt, Wkt, Wvt,
                                              b_q, b_k, b_v, Qp, Kp, Vpt);

  attn_kernel<<<dim3(32, 16), 512, 0, stream>>>(Qp, Kp, Vpt, concat);

  gemm_out<<<dim3(128, 4), 256, 0, stream>>>(concat, Wot, b_o, out);
}